// Round 4
// baseline (1440.769 us; speedup 1.0000x reference)
//
#include <hip/hip_runtime.h>
#include <hip/hip_bf16.h>

// SNN 3-layer LIF MLP, T=10, fp32 reference. All GEMMs on MFMA bf16 with
// exact 3-plane bf16 splits (Sterbenz residuals; hi+mid+lo == fp32 weight).
// R4: software-pipelined K-loop — double-buffered LDS, global_load_lds
// prefetch of tile k+1 issued BEFORE compute of tile k, ONE barrier/iter.
// Wave tile 64x32 (4x2 frags), 2 waves/block (128 thr), block tile 64x64.
// XOR-granule LDS swizzle (slot = s*8 + ((g+s)&7)) -> measured 0 conflicts.
// XCD swizzle: blockIdx%8 keys a contiguous N-slab per XCD L2.

typedef __attribute__((ext_vector_type(8))) short short8;
typedef float f32x4 __attribute__((ext_vector_type(4)));

#ifndef __has_builtin
#define __has_builtin(x) 0
#endif
#if __has_builtin(__builtin_amdgcn_global_load_lds)
#define HAS_GLLDS 1
#else
#define HAS_GLLDS 0
#endif

// ------------------------------------------------------------- unified MFMA+LIF
// MODE 0: 1 A-plane x 3 B-planes  (L2, L3)
// MODE 1: 3 A-planes x 3 B-planes, 6 significant pairs (L1)
template<int MODE>
__global__ __launch_bounds__(128)
void mfma_lif(const __hip_bfloat16* __restrict__ A, size_t aStride, int lda,
              const __hip_bfloat16* __restrict__ B, size_t bStride, int ldb,
              int K,
              const float* __restrict__ bias,
              float* __restrict__ cacc,            // nullable (L1 running charge)
              float* __restrict__ v,
              __hip_bfloat16* __restrict__ sbf,    // nullable spikes (bf16)
              float* __restrict__ sf32,            // nullable spikes (f32, n<Nreal)
              int Npad, int Nreal, int ls)         // ls = log2(n_tiles per XCD)
{
    constexpr int NA = MODE ? 3 : 1;
    constexpr int NB = 3;
    constexpr int NT = NA + NB;

    __shared__ __align__(16) char tiles[2 * NT * 4096];

    const int tid = threadIdx.x;
    const int b   = blockIdx.x;
    const int xcd = b & 7, ii = b >> 3;
    const int ntp = 1 << ls;
    const int n_tile = xcd * ntp + (ii & (ntp - 1));
    const int m_tile = ii >> ls;
    const int m0 = m_tile * 64, n0 = n_tile * 64;

    // ---- staging: 256 granule-slots per tile, 2 per thread (h = 0,1)
    int row[2], chk[2];
    #pragma unroll
    for (int h = 0; h < 2; ++h) {
        const int s  = tid + h * 128;
        const int ss = s >> 3;
        const int gg = ((s & 7) - ss) & 7;
        row[h] = 2 * ss + (gg >> 2);
        chk[h] = gg & 3;
    }
    const int wb = (tid & ~63) * 16;   // wave-uniform LDS dest base (h adds 2048)

    const __hip_bfloat16* srcA[NA][2];
    const __hip_bfloat16* srcB[NB][2];
    #pragma unroll
    for (int p = 0; p < NA; ++p)
        #pragma unroll
        for (int h = 0; h < 2; ++h)
            srcA[p][h] = A + p * aStride + (size_t)(m0 + row[h]) * lda + chk[h] * 8;
    #pragma unroll
    for (int q = 0; q < NB; ++q)
        #pragma unroll
        for (int h = 0; h < 2; ++h)
            srcB[q][h] = B + q * bStride + (size_t)(n0 + row[h]) * ldb + chk[h] * 8;

    auto stage = [&](int buf, int kk) {
        char* base = tiles + buf * (NT * 4096) + wb;
        #pragma unroll
        for (int p = 0; p < NA; ++p) {
            #pragma unroll
            for (int h = 0; h < 2; ++h) {
#if HAS_GLLDS
                __builtin_amdgcn_global_load_lds(
                    (const __attribute__((address_space(1))) void*)(srcA[p][h] + kk),
                    (__attribute__((address_space(3))) void*)(base + p * 4096 + h * 2048),
                    16, 0, 0);
#else
                *(float4*)(tiles + buf * (NT * 4096) + p * 4096 + (tid + h * 128) * 16) =
                    *(const float4*)(srcA[p][h] + kk);
#endif
            }
        }
        #pragma unroll
        for (int q = 0; q < NB; ++q) {
            #pragma unroll
            for (int h = 0; h < 2; ++h) {
#if HAS_GLLDS
                __builtin_amdgcn_global_load_lds(
                    (const __attribute__((address_space(1))) void*)(srcB[q][h] + kk),
                    (__attribute__((address_space(3))) void*)(base + (NA + q) * 4096 + h * 2048),
                    16, 0, 0);
#else
                *(float4*)(tiles + buf * (NT * 4096) + (NA + q) * 4096 + (tid + h * 128) * 16) =
                    *(const float4*)(srcB[q][h] + kk);
#endif
            }
        }
    };

    // ---- fragment geometry: wave tile 64(m) x 32(n)
    const int lane = tid & 63;
    const int w    = tid >> 6;         // 0,1
    const int wn   = w * 32;
    const int lm   = lane & 15, ck = lane >> 4;

    int aSlot[4], bSlot[2];
    #pragma unroll
    for (int i = 0; i < 4; ++i) {
        const int r = i * 16 + lm, s2 = r >> 1;
        aSlot[i] = (s2 * 8 + ((((r & 1) << 2) + ck + s2) & 7)) * 16;
    }
    #pragma unroll
    for (int j = 0; j < 2; ++j) {
        const int r = wn + j * 16 + lm, s2 = r >> 1;
        bSlot[j] = (s2 * 8 + ((((r & 1) << 2) + ck + s2) & 7)) * 16;
    }

    f32x4 acc[4][2] = {};

    // ---- pipelined K-loop: prefetch (k+1) -> buf^1, compute k from buf
    stage(0, 0);
    __syncthreads();

    const int nIter = K / 32;
    for (int it = 0; it < nIter; ++it) {
        const int buf = it & 1;
        const int kn  = (it + 1 < nIter) ? (it + 1) * 32 : 0;  // dummy-safe wrap
        stage(buf ^ 1, kn);

        const char* tb = tiles + buf * (NT * 4096);
        short8 aF[NA][4], bF[NB][2];
        #pragma unroll
        for (int p = 0; p < NA; ++p)
            #pragma unroll
            for (int i = 0; i < 4; ++i)
                aF[p][i] = *(const short8*)(tb + p * 4096 + aSlot[i]);
        #pragma unroll
        for (int q = 0; q < NB; ++q)
            #pragma unroll
            for (int j = 0; j < 2; ++j)
                bF[q][j] = *(const short8*)(tb + (NA + q) * 4096 + bSlot[j]);

        if (MODE == 0) {
            #pragma unroll
            for (int q = 0; q < 3; ++q)
                #pragma unroll
                for (int i = 0; i < 4; ++i)
                    #pragma unroll
                    for (int j = 0; j < 2; ++j)
                        acc[i][j] = __builtin_amdgcn_mfma_f32_16x16x32_bf16(
                            aF[0][i], bF[q][j], acc[i][j], 0, 0, 0);
        } else {
            constexpr int PA[6] = {0,0,1,0,2,1}, PB[6] = {0,1,0,2,0,1};
            #pragma unroll
            for (int pp = 0; pp < 6; ++pp)
                #pragma unroll
                for (int i = 0; i < 4; ++i)
                    #pragma unroll
                    for (int j = 0; j < 2; ++j)
                        acc[i][j] = __builtin_amdgcn_mfma_f32_16x16x32_bf16(
                            aF[PA[pp] % NA][i], bF[PB[pp]][j], acc[i][j], 0, 0, 0);
        }
        __syncthreads();   // waves done reading buf; prefetch into buf^1 drained
    }

    // ---- LIF epilogue. C/D layout: col = lane&15, row = (lane>>4)*4 + reg
    const int rq = (lane >> 4) * 4;
    #pragma unroll
    for (int i = 0; i < 4; ++i) {
        #pragma unroll
        for (int j = 0; j < 2; ++j) {
            const int n = n0 + wn + j * 16 + lm;
            const float bb = bias[n];
            #pragma unroll
            for (int r = 0; r < 4; ++r) {
                const int m = m0 + i * 16 + rq + r;
                const size_t idx = (size_t)m * Npad + n;
                float dot = acc[i][j][r];
                if (cacc) { dot += cacc[idx]; cacc[idx] = dot; }
                const float ch = dot + bb;
                const float vv = (v[idx] + ch) * 0.5f;
                const float sp = (vv >= 1.0f) ? 1.0f : 0.0f;
                v[idx] = (sp != 0.0f) ? 0.0f : vv;
                if (sbf)  sbf[idx] = __float2bfloat16(sp);
                if (sf32 && n < Nreal) sf32[(size_t)m * Nreal + n] = sp;
            }
        }
    }
}

// ---------------------------------------------------------------- weight splits
__device__ __forceinline__ void bf16split3(float val, __hip_bfloat16& hi,
                                           __hip_bfloat16& mid, __hip_bfloat16& lo) {
    hi = __float2bfloat16(val);
    const float r1 = val - __bfloat162float(hi);
    mid = __float2bfloat16(r1);
    const float r2 = r1 - __bfloat162float(mid);
    lo = __float2bfloat16(r2);
}

// W [K][Nreal] fp32 -> 3 planes [Npad][K] bf16 (NT)
__global__ __launch_bounds__(256)
void split3_t(const float* __restrict__ W, int K, int Nreal, int Npad,
              __hip_bfloat16* __restrict__ out)
{
    __shared__ float t[32][33];
    const int k0 = blockIdx.x * 32, n0 = blockIdx.y * 32;
    const int tx = threadIdx.x & 31, ty = threadIdx.x >> 5;
    #pragma unroll
    for (int i = 0; i < 4; ++i) {
        const int k = k0 + ty + i * 8, n = n0 + tx;
        t[ty + i * 8][tx] = (n < Nreal) ? W[(size_t)k * Nreal + n] : 0.f;
    }
    __syncthreads();
    const size_t plane = (size_t)Npad * K;
    #pragma unroll
    for (int i = 0; i < 4; ++i) {
        const int n = n0 + ty + i * 8, k = k0 + tx;
        __hip_bfloat16 hi, mid, lo;
        bf16split3(t[tx][ty + i * 8], hi, mid, lo);
        const size_t idx = (size_t)n * K + k;
        out[idx] = hi; out[plane + idx] = mid; out[2 * plane + idx] = lo;
    }
}

// W1 [4000][2048] -> 3 planes [2048][4160] bf16 (NT, per-chunk K padded 400->416)
__global__ __launch_bounds__(256)
void split3_w1(const float* __restrict__ W1, __hip_bfloat16* __restrict__ out)
{
    __shared__ float t[32][33];
    const int kk0 = blockIdx.x * 32, n0 = blockIdx.y * 32;
    const int tx = threadIdx.x & 31, ty = threadIdx.x >> 5;
    #pragma unroll
    for (int i = 0; i < 4; ++i) {
        const int kk = kk0 + ty + i * 8;
        const int tt = kk / 416, j = kk - tt * 416;
        t[ty + i * 8][tx] = (j < 400) ? W1[(size_t)(tt * 400 + j) * 2048 + (n0 + tx)] : 0.f;
    }
    __syncthreads();
    const size_t plane = (size_t)2048 * 4160;
    #pragma unroll
    for (int i = 0; i < 4; ++i) {
        const int n = n0 + ty + i * 8, kk = kk0 + tx;
        __hip_bfloat16 hi, mid, lo;
        bf16split3(t[tx][ty + i * 8], hi, mid, lo);
        const size_t idx = (size_t)n * 4160 + kk;
        out[idx] = hi; out[plane + idx] = mid; out[2 * plane + idx] = lo;
    }
}

// x [1024][4000] -> 3 planes [1024][4160] bf16 (per-chunk K padded)
__global__ __launch_bounds__(256)
void splitx(const float* __restrict__ x, __hip_bfloat16* __restrict__ out)
{
    const int id = blockIdx.x * 256 + threadIdx.x;
    if (id >= 1024 * 4160) return;
    const int m = id / 4160, kk = id - m * 4160;
    const int tt = kk / 416, j = kk - tt * 416;
    const float val = (j < 400) ? x[(size_t)m * 4000 + tt * 400 + j] : 0.f;
    const size_t PS = (size_t)1024 * 4160;
    __hip_bfloat16 hi, mid, lo;
    bf16split3(val, hi, mid, lo);
    out[id] = hi; out[PS + id] = mid; out[2 * PS + id] = lo;
}

// -------------------------------------------------- fallback L1 fp32 VALU GEMM
#define BM 64
#define BN 64
#define BK 16
#define TM 4
#define TN 4
__global__ __launch_bounds__(256)
void gemm_lif_f32(const float* __restrict__ A, int lda,
                  const float* __restrict__ B, int ldb,
                  const float* __restrict__ bias,
                  float* __restrict__ cacc, float* __restrict__ v,
                  __hip_bfloat16* __restrict__ s, int M, int N, int K)
{
    __shared__ float As[BK][BM + 4];
    __shared__ float Bs[BK][BN + 4];
    const int tid = threadIdx.x;
    const int tx = tid & 15, ty = tid >> 4;
    const int row0 = blockIdx.y * BM, col0 = blockIdx.x * BN;
    const int am = tid >> 2, ak = (tid & 3) * 4;
    const int bk = tid >> 4, bn = (tid & 15) * 4;
    float acc[TM][TN];
    #pragma unroll
    for (int i = 0; i < TM; ++i)
        #pragma unroll
        for (int j = 0; j < TN; ++j) acc[i][j] = 0.f;
    for (int k0 = 0; k0 < K; k0 += BK) {
        const float4 a4 = *(const float4*)(A + (size_t)(row0 + am) * lda + (k0 + ak));
        As[ak + 0][am] = a4.x; As[ak + 1][am] = a4.y;
        As[ak + 2][am] = a4.z; As[ak + 3][am] = a4.w;
        *(float4*)&Bs[bk][bn] = *(const float4*)(B + (size_t)(k0 + bk) * ldb + (col0 + bn));
        __syncthreads();
        #pragma unroll
        for (int kk = 0; kk < BK; ++kk) {
            float a_frag[TM], b_frag[TN];
            #pragma unroll
            for (int i = 0; i < TM; ++i) a_frag[i] = As[kk][ty * TM + i];
            #pragma unroll
            for (int j = 0; j < TN; ++j) b_frag[j] = Bs[kk][tx * TN + j];
            #pragma unroll
            for (int i = 0; i < TM; ++i)
                #pragma unroll
                for (int j = 0; j < TN; ++j) acc[i][j] += a_frag[i] * b_frag[j];
        }
        __syncthreads();
    }
    #pragma unroll
    for (int i = 0; i < TM; ++i) {
        const int r = row0 + ty * TM + i;
        #pragma unroll
        for (int j = 0; j < TN; ++j) {
            const int c = col0 + tx * TN + j;
            const size_t idx = (size_t)r * N + c;
            float dot = acc[i][j] + cacc[idx];
            cacc[idx] = dot;
            const float ch = dot + bias[c];
            const float vv = (v[idx] + ch) * 0.5f;
            const float sp = (vv >= 1.0f) ? 1.0f : 0.0f;
            v[idx] = (sp != 0.0f) ? 0.0f : vv;
            s[idx] = __float2bfloat16(sp);
        }
    }
}

// --------------------------------------------------------------------- launch
extern "C" void kernel_launch(void* const* d_in, const int* in_sizes, int n_in,
                              void* d_out, int out_size, void* d_ws, size_t ws_size,
                              hipStream_t stream) {
    const float* x  = (const float*)d_in[0];
    const float* W1 = (const float*)d_in[1];
    const float* b1 = (const float*)d_in[2];
    const float* W2 = (const float*)d_in[3];
    const float* b2 = (const float*)d_in[4];
    const float* W3 = (const float*)d_in[5];
    const float* b3 = (const float*)d_in[6];
    float* out = (float*)d_out;

    const int Bb = 1024, D = 4000, H = 2048, O = 1000, Op = 1024, T = 10, CH = 400;
    const int KP = 4160, CHP = 416;
    const size_t BH = (size_t)Bb * H, BOp = (size_t)Bb * Op;

    float* ws = (float*)d_ws;
    float* c1  = ws;                       // BH
    float* v1  = c1 + BH;                  // BH
    float* v2  = v1 + BH;                  // BH
    float* v3  = v2 + BH;                  // BOp
    float* b3p = v3 + BOp;                 // 1024
    float* zend = b3p + 1024;
    __hip_bfloat16* s1  = (__hip_bfloat16*)zend;                 // BH
    __hip_bfloat16* s2  = s1 + BH;                               // BH
    __hip_bfloat16* w2s = s2 + BH;                               // 3*H*H
    __hip_bfloat16* w3s = w2s + (size_t)3 * H * H;               // 3*Op*H
    __hip_bfloat16* w1s = w3s + (size_t)3 * Op * H;              // 3*H*KP
    __hip_bfloat16* xs  = w1s + (size_t)3 * H * KP;              // 3*Bb*KP
    const size_t zero_bytes = ((size_t)3 * BH + BOp + 1024) * sizeof(float);
    const size_t need_big = zero_bytes +
        (2 * BH + (size_t)3 * H * H + (size_t)3 * Op * H +
         (size_t)3 * H * KP + (size_t)3 * Bb * KP) * sizeof(__hip_bfloat16);
    const bool bigws = ws_size >= need_big;

    hipMemsetAsync(d_ws, 0, zero_bytes, stream);
    hipMemcpyAsync(b3p, b3, O * sizeof(float), hipMemcpyDeviceToDevice, stream);

    split3_t<<<dim3(H / 32, H / 32), 256, 0, stream>>>(W2, H, H, H, w2s);
    split3_t<<<dim3(H / 32, Op / 32), 256, 0, stream>>>(W3, H, O, Op, w3s);
    if (bigws) {
        split3_w1<<<dim3(KP / 32, H / 32), 256, 0, stream>>>(W1, w1s);
        splitx<<<dim3((Bb * KP + 255) / 256), 256, 0, stream>>>(x, xs);
    }

    const size_t PSx = (size_t)Bb * KP;
    const size_t PSw1 = (size_t)H * KP;
    const dim3 blk(128);
    const dim3 g1f(H / BN, Bb / BM);

    for (int t = 0; t < T; ++t) {
        if (bigws) {
            mfma_lif<1><<<512, blk, 0, stream>>>(
                xs + t * CHP, PSx, KP, w1s + t * CHP, PSw1, KP, CHP,
                b1, c1, v1, s1, nullptr, H, H, 2);
        } else {
            gemm_lif_f32<<<g1f, 256, 0, stream>>>(x + t * CH, D,
                                                  W1 + (size_t)t * CH * H, H,
                                                  b1, c1, v1, s1, Bb, H, CH);
        }
        mfma_lif<0><<<512, blk, 0, stream>>>(
            s1, 0, H, w2s, (size_t)H * H, H, H,
            b2, nullptr, v2, s2, nullptr, H, H, 2);
        mfma_lif<0><<<256, blk, 0, stream>>>(
            s2, 0, H, w3s, (size_t)Op * H, H, H,
            b3p, nullptr, v3, nullptr, (t == T - 1) ? out : nullptr, Op, O, 1);
    }
}

// Round 5
// 723.530 us; speedup vs baseline: 1.9913x; 1.9913x over previous
//
#include <hip/hip_runtime.h>
#include <hip/hip_bf16.h>

// SNN 3-layer LIF MLP, T=10, fp32 reference.
// R5 restructure: T-steps STACKED into M=10240 GEMMs (charges don't depend on
// same-layer membrane state):
//   P_t  = x_chunk_t(3 bf16 planes) @ W1_chunk_t(3 planes), 6 pairs  [1 dispatch]
//   LIF1 scan over t (prefix-sum P_t + LIF) -> s1_t (bf16)           [elementwise]
//   C2   = s1_stack @ W2(3 planes)                                    [1 dispatch]
//   LIF2 scan -> s2_t;  C3 = s2_stack @ W3(3 planes); LIF3 -> out
// GEMM: 128x128 block tile, 256 thr, m97 2-barrier K-loop, global_load_lds 16B
// into the XOR-granule-swizzled LDS layout (measured 0 bank conflicts in R3).
// Numerics: identical MFMA chain order / prefix order / LIF math as R3 (absmax 0).

typedef __attribute__((ext_vector_type(8))) short short8;
typedef __attribute__((ext_vector_type(4))) float f32x4;
typedef __attribute__((ext_vector_type(4))) unsigned short us4;

#ifndef __has_builtin
#define __has_builtin(x) 0
#endif
#if __has_builtin(__builtin_amdgcn_global_load_lds)
#define HAS_GLLDS 1
#else
#define HAS_GLLDS 0
#endif

// ------------------------------------------------------------------ GEMM
// MODE 0: 1 A-plane x 3 B-planes (spikes)   wave tile 128m x 32n (FM=8,FN=2)
// MODE 1: 3 A-planes x 3 B-planes, 6 pairs  wave tile 64x64      (FM=4,FN=4)
//         per-t K-slice: t = m0>>10, kbase = t*kChunk
template<int MODE>
__global__ __launch_bounds__(256)
void gemm_planes(const __hip_bfloat16* __restrict__ A, size_t aStride, int lda,
                 const __hip_bfloat16* __restrict__ B, size_t bStride, int ldb,
                 int K, int kChunk,
                 float* __restrict__ C, int Npad, int ls)
{
    constexpr int NA = MODE ? 3 : 1;
    constexpr int FM = MODE ? 4 : 8;
    constexpr int FN = MODE ? 4 : 2;

    __shared__ __align__(16) char tiles[(NA + 3) * 8192];

    const int tid = threadIdx.x;
    const int b   = blockIdx.x;
    const int xcd = b & 7, ii = b >> 3;
    const int ntp = 1 << ls;
    const int n_tile = xcd * ntp + (ii & (ntp - 1));
    const int m_tile = ii >> ls;
    const int m0 = m_tile * 128, n0 = n_tile * 128;

    const int t     = MODE ? (m0 >> 10) : 0;
    const int kbase = MODE ? t * kChunk : 0;
    const int arow0 = MODE ? (m0 & 1023) : m0;

    // staging decode: thread fills granule slots {tid, tid+256} of each plane
    int srow[2], schk[2];
    #pragma unroll
    for (int h = 0; h < 2; ++h) {
        const int s   = h * 256 + tid;
        const int sub = s >> 8, sp = s & 255;
        const int ss  = sp >> 3, gg = ((sp & 7) - ss) & 7;
        srow[h] = sub * 64 + 2 * ss + (gg >> 2);
        schk[h] = gg & 3;
    }
    const int wbase = (tid & ~63) * 16;   // wave-uniform LDS dest base

    const __hip_bfloat16* srcA[NA][2];
    const __hip_bfloat16* srcB[3][2];
    #pragma unroll
    for (int p = 0; p < NA; ++p)
        #pragma unroll
        for (int h = 0; h < 2; ++h)
            srcA[p][h] = A + p * aStride + (size_t)(arow0 + srow[h]) * lda
                           + kbase + schk[h] * 8;
    #pragma unroll
    for (int q = 0; q < 3; ++q)
        #pragma unroll
        for (int h = 0; h < 2; ++h)
            srcB[q][h] = B + q * bStride + (size_t)(n0 + srow[h]) * ldb
                           + kbase + schk[h] * 8;

    // fragment geometry
    const int lane = tid & 63, w = tid >> 6;
    const int wm = MODE ? ((w >> 1) * 64) : 0;
    const int wn = MODE ? ((w & 1) * 64) : (w * 32);
    const int lm = lane & 15, ck = lane >> 4;

    int aOff[FM], bOff[FN];
    #pragma unroll
    for (int i = 0; i < FM; ++i) {
        const int r = wm + i * 16 + lm, sub = r >> 6, rr = r & 63, s2 = rr >> 1;
        aOff[i] = sub * 4096 + (s2 * 8 + ((((rr & 1) << 2) + ck + s2) & 7)) * 16;
    }
    #pragma unroll
    for (int j = 0; j < FN; ++j) {
        const int r = wn + j * 16 + lm, sub = r >> 6, rr = r & 63, s2 = rr >> 1;
        bOff[j] = sub * 4096 + (s2 * 8 + ((((rr & 1) << 2) + ck + s2) & 7)) * 16;
    }

    f32x4 acc[FM][FN] = {};

    const int nIter = K / 32;
    for (int it = 0; it < nIter; ++it) {
        const int kk = it * 32;
        #pragma unroll
        for (int p = 0; p < NA; ++p) {
            #pragma unroll
            for (int h = 0; h < 2; ++h) {
#if HAS_GLLDS
                __builtin_amdgcn_global_load_lds(
                    (const __attribute__((address_space(1))) void*)(srcA[p][h] + kk),
                    (__attribute__((address_space(3))) void*)(tiles + p * 8192 + h * 4096 + wbase),
                    16, 0, 0);
#else
                *(float4*)(tiles + p * 8192 + (h * 256 + tid) * 16) =
                    *(const float4*)(srcA[p][h] + kk);
#endif
            }
        }
        #pragma unroll
        for (int q = 0; q < 3; ++q) {
            #pragma unroll
            for (int h = 0; h < 2; ++h) {
#if HAS_GLLDS
                __builtin_amdgcn_global_load_lds(
                    (const __attribute__((address_space(1))) void*)(srcB[q][h] + kk),
                    (__attribute__((address_space(3))) void*)(tiles + (NA + q) * 8192 + h * 4096 + wbase),
                    16, 0, 0);
#else
                *(float4*)(tiles + (NA + q) * 8192 + (h * 256 + tid) * 16) =
                    *(const float4*)(srcB[q][h] + kk);
#endif
            }
        }
        __syncthreads();

        short8 aF[NA][FM], bF[3][FN];
        #pragma unroll
        for (int p = 0; p < NA; ++p)
            #pragma unroll
            for (int i = 0; i < FM; ++i)
                aF[p][i] = *(const short8*)(tiles + p * 8192 + aOff[i]);
        #pragma unroll
        for (int q = 0; q < 3; ++q)
            #pragma unroll
            for (int j = 0; j < FN; ++j)
                bF[q][j] = *(const short8*)(tiles + (NA + q) * 8192 + bOff[j]);

        if (MODE == 0) {
            #pragma unroll
            for (int q = 0; q < 3; ++q)
                #pragma unroll
                for (int i = 0; i < FM; ++i)
                    #pragma unroll
                    for (int j = 0; j < FN; ++j)
                        acc[i][j] = __builtin_amdgcn_mfma_f32_16x16x32_bf16(
                            aF[0][i], bF[q][j], acc[i][j], 0, 0, 0);
        } else {
            constexpr int PA[6] = {0,0,1,0,2,1}, PB[6] = {0,1,0,2,0,1};
            #pragma unroll
            for (int pp = 0; pp < 6; ++pp)
                #pragma unroll
                for (int i = 0; i < FM; ++i)
                    #pragma unroll
                    for (int j = 0; j < FN; ++j)
                        acc[i][j] = __builtin_amdgcn_mfma_f32_16x16x32_bf16(
                            aF[PA[pp] % NA][i], bF[PB[pp]][j], acc[i][j], 0, 0, 0);
        }
        __syncthreads();
    }

    // raw dot write. C/D layout: col = lane&15, row = (lane>>4)*4 + reg
    const int rq = ck * 4;
    #pragma unroll
    for (int i = 0; i < FM; ++i) {
        #pragma unroll
        for (int j = 0; j < FN; ++j) {
            const int n = n0 + wn + j * 16 + lm;
            #pragma unroll
            for (int r = 0; r < 4; ++r) {
                const int m = m0 + wm + i * 16 + rq + r;
                C[(size_t)m * Npad + n] = acc[i][j][r];
            }
        }
    }
}

// ------------------------------------------------------------------ LIF scan
// C stacked [T*1024][Hpad]; per (batch,neuron) scan over t with v in registers.
__global__ __launch_bounds__(256)
void lif_scan(const float* __restrict__ C, const float* __restrict__ bias,
              unsigned short* __restrict__ sout,   // bf16 spike bits, nullable
              float* __restrict__ fout,            // nullable: t=9, n<Nreal
              int Hpad, int Nreal, int prefix)
{
    const int W4 = Hpad >> 2;
    const int idx = blockIdx.x * 256 + threadIdx.x;
    if (idx >= (W4 << 10)) return;
    const int bb = idx / W4, n4 = idx - bb * W4;
    const float4 b4 = *(const float4*)(bias + n4 * 4);
    const float bs[4] = {b4.x, b4.y, b4.z, b4.w};
    float v[4] = {0.f,0.f,0.f,0.f}, c[4] = {0.f,0.f,0.f,0.f};
    for (int t = 0; t < 10; ++t) {
        const size_t row = (size_t)((t << 10) + bb);
        const float4 p4 = *(const float4*)(C + row * Hpad + n4 * 4);
        const float pv[4] = {p4.x, p4.y, p4.z, p4.w};
        float sv[4];
        #pragma unroll
        for (int e = 0; e < 4; ++e) {
            c[e] = prefix ? (c[e] + pv[e]) : pv[e];
            const float vv = (v[e] + (c[e] + bs[e])) * 0.5f;
            const float sp = (vv >= 1.0f) ? 1.0f : 0.0f;
            v[e] = (sp != 0.0f) ? 0.0f : vv;
            sv[e] = sp;
        }
        if (sout) {
            us4 o;
            #pragma unroll
            for (int e = 0; e < 4; ++e) o[e] = (sv[e] != 0.0f) ? 0x3F80 : 0;
            *(us4*)(sout + row * Hpad + n4 * 4) = o;
        }
        if (fout && t == 9) {
            #pragma unroll
            for (int e = 0; e < 4; ++e) {
                const int n = n4 * 4 + e;
                if (n < Nreal) fout[(size_t)bb * Nreal + n] = sv[e];
            }
        }
    }
}

// ------------------------------------------------------------------ splits
__device__ __forceinline__ void bf16split3(float val, __hip_bfloat16& hi,
                                           __hip_bfloat16& mid, __hip_bfloat16& lo) {
    hi = __float2bfloat16(val);
    const float r1 = val - __bfloat162float(hi);
    mid = __float2bfloat16(r1);
    const float r2 = r1 - __bfloat162float(mid);
    lo = __float2bfloat16(r2);
}

// W [K][Nreal] fp32 -> 3 planes [Npad][K] bf16 (NT)
__global__ __launch_bounds__(256)
void split3_t(const float* __restrict__ W, int K, int Nreal, int Npad,
              __hip_bfloat16* __restrict__ out)
{
    __shared__ float tl[32][33];
    const int k0 = blockIdx.x * 32, n0 = blockIdx.y * 32;
    const int tx = threadIdx.x & 31, ty = threadIdx.x >> 5;
    #pragma unroll
    for (int i = 0; i < 4; ++i) {
        const int k = k0 + ty + i * 8, n = n0 + tx;
        tl[ty + i * 8][tx] = (n < Nreal) ? W[(size_t)k * Nreal + n] : 0.f;
    }
    __syncthreads();
    const size_t plane = (size_t)Npad * K;
    #pragma unroll
    for (int i = 0; i < 4; ++i) {
        const int n = n0 + ty + i * 8, k = k0 + tx;
        __hip_bfloat16 hi, mid, lo;
        bf16split3(tl[tx][ty + i * 8], hi, mid, lo);
        const size_t idx = (size_t)n * K + k;
        out[idx] = hi; out[plane + idx] = mid; out[2 * plane + idx] = lo;
    }
}

// W1 [4000][2048] -> 3 planes [2048][4160] (NT, per-chunk K padded 400->416)
__global__ __launch_bounds__(256)
void split3_w1(const float* __restrict__ W1, __hip_bfloat16* __restrict__ out)
{
    __shared__ float tl[32][33];
    const int kk0 = blockIdx.x * 32, n0 = blockIdx.y * 32;
    const int tx = threadIdx.x & 31, ty = threadIdx.x >> 5;
    #pragma unroll
    for (int i = 0; i < 4; ++i) {
        const int kk = kk0 + ty + i * 8;
        const int tt = kk / 416, j = kk - tt * 416;
        tl[ty + i * 8][tx] = (j < 400) ? W1[(size_t)(tt * 400 + j) * 2048 + (n0 + tx)] : 0.f;
    }
    __syncthreads();
    const size_t plane = (size_t)2048 * 4160;
    #pragma unroll
    for (int i = 0; i < 4; ++i) {
        const int n = n0 + ty + i * 8, kk = kk0 + tx;
        __hip_bfloat16 hi, mid, lo;
        bf16split3(tl[tx][ty + i * 8], hi, mid, lo);
        const size_t idx = (size_t)n * 4160 + kk;
        out[idx] = hi; out[plane + idx] = mid; out[2 * plane + idx] = lo;
    }
}

// x [1024][4000] -> 3 planes [1024][4160]
__global__ __launch_bounds__(256)
void splitx(const float* __restrict__ x, __hip_bfloat16* __restrict__ out)
{
    const int id = blockIdx.x * 256 + threadIdx.x;
    if (id >= 1024 * 4160) return;
    const int m = id / 4160, kk = id - m * 4160;
    const int tt = kk / 416, j = kk - tt * 416;
    const float val = (j < 400) ? x[(size_t)m * 4000 + tt * 400 + j] : 0.f;
    const size_t PS = (size_t)1024 * 4160;
    __hip_bfloat16 hi, mid, lo;
    bf16split3(val, hi, mid, lo);
    out[id] = hi; out[PS + id] = mid; out[2 * PS + id] = lo;
}

// -------------------------------------- fallback fp32 path (small workspace)
__global__ __launch_bounds__(256)
void gemm_lif_f32fb(const float* __restrict__ A, int lda,
                    const float* __restrict__ B, int ldb,
                    const float* __restrict__ bias,
                    float* __restrict__ cacc, float* __restrict__ v,
                    float* __restrict__ s, int M, int N, int K)
{
    __shared__ float As[16][68];
    __shared__ float Bs[16][68];
    const int tid = threadIdx.x;
    const int tx = tid & 15, ty = tid >> 4;
    const int row0 = blockIdx.y * 64, col0 = blockIdx.x * 64;
    const int am = tid >> 2, ak = (tid & 3) * 4;
    const int bk = tid >> 4, bn = (tid & 15) * 4;
    float acc[4][4];
    #pragma unroll
    for (int i = 0; i < 4; ++i)
        #pragma unroll
        for (int j = 0; j < 4; ++j) acc[i][j] = 0.f;
    for (int k0 = 0; k0 < K; k0 += 16) {
        const float4 a4 = *(const float4*)(A + (size_t)(row0 + am) * lda + (k0 + ak));
        As[ak + 0][am] = a4.x; As[ak + 1][am] = a4.y;
        As[ak + 2][am] = a4.z; As[ak + 3][am] = a4.w;
        {
            const int col = col0 + bn;
            const float* bp = B + (size_t)(k0 + bk) * ldb + col;
            float4 b4;
            if (col + 3 < N) b4 = *(const float4*)bp;
            else {
                b4.x = (col + 0 < N) ? bp[0] : 0.f;
                b4.y = (col + 1 < N) ? bp[1] : 0.f;
                b4.z = (col + 2 < N) ? bp[2] : 0.f;
                b4.w = 0.f;
            }
            *(float4*)&Bs[bk][bn] = b4;
        }
        __syncthreads();
        #pragma unroll
        for (int kk = 0; kk < 16; ++kk) {
            float af[4], bf[4];
            #pragma unroll
            for (int i = 0; i < 4; ++i) af[i] = As[kk][ty * 4 + i];
            #pragma unroll
            for (int j = 0; j < 4; ++j) bf[j] = Bs[kk][tx * 4 + j];
            #pragma unroll
            for (int i = 0; i < 4; ++i)
                #pragma unroll
                for (int j = 0; j < 4; ++j) acc[i][j] += af[i] * bf[j];
        }
        __syncthreads();
    }
    #pragma unroll
    for (int i = 0; i < 4; ++i) {
        const int r = row0 + ty * 4 + i;
        #pragma unroll
        for (int j = 0; j < 4; ++j) {
            const int cidx = col0 + tx * 4 + j;
            if (cidx >= N) continue;
            const size_t idx = (size_t)r * N + cidx;
            float dot = acc[i][j];
            if (cacc) { dot += cacc[idx]; cacc[idx] = dot; }
            const float ch = dot + bias[cidx];
            const float vv = (v[idx] + ch) * 0.5f;
            const float sp = (vv >= 1.0f) ? 1.0f : 0.0f;
            v[idx] = (sp != 0.0f) ? 0.0f : vv;
            s[idx] = sp;
        }
    }
}

// --------------------------------------------------------------------- launch
extern "C" void kernel_launch(void* const* d_in, const int* in_sizes, int n_in,
                              void* d_out, int out_size, void* d_ws, size_t ws_size,
                              hipStream_t stream) {
    const float* x  = (const float*)d_in[0];
    const float* W1 = (const float*)d_in[1];
    const float* b1 = (const float*)d_in[2];
    const float* W2 = (const float*)d_in[3];
    const float* b2 = (const float*)d_in[4];
    const float* W3 = (const float*)d_in[5];
    const float* b3 = (const float*)d_in[6];
    float* out = (float*)d_out;

    const int Bb = 1024, D = 4000, H = 2048, O = 1000, Op = 1024, T = 10;
    const int KP = 4160, CHP = 416, CH = 400;
    const int MS = T * Bb;   // 10240 stacked rows

    // ---- workspace layout (byte offsets)
    char* base = (char*)d_ws;
    __hip_bfloat16* w2s = (__hip_bfloat16*)(base);                 // 25,165,824
    __hip_bfloat16* w3s = (__hip_bfloat16*)(base + 25165824);      // 12,582,912
    float*          b3p = (float*)(base + 37748736);               //      4,096
    __hip_bfloat16* s1  = (__hip_bfloat16*)(base + 37752832);      // 41,943,040
    float*          P   = (float*)(base + 79695872);               // 83,886,080 (C2 alias)
    __hip_bfloat16* xs  = (__hip_bfloat16*)(base + 163581952);     // 25,559,040
    __hip_bfloat16* w1s = (__hip_bfloat16*)(base + 189140992);     // 51,118,080
    __hip_bfloat16* s2  = xs;          // alias: xs/w1s dead after L1 gemm
    float*          C3  = (float*)s1;  // alias: s1 dead after L2 gemm
    const size_t need = 240259072;

    if (ws_size < need) {
        // fp32 VALU fallback (R1 path, ~3.5 ms, 46 MB)
        const size_t BH = (size_t)Bb * H, BO = (size_t)Bb * O;
        float* ws = (float*)d_ws;
        float* c1 = ws;        float* v1 = c1 + BH;  float* s1f = v1 + BH;
        float* v2 = s1f + BH;  float* s2f = v2 + BH; float* v3 = s2f + BH;
        hipMemsetAsync(d_ws, 0, (5 * BH + BO) * sizeof(float), stream);
        const dim3 blk(256);
        for (int t = 0; t < T; ++t) {
            gemm_lif_f32fb<<<dim3(H / 64, Bb / 64), blk, 0, stream>>>(
                x + t * CH, D, W1 + (size_t)t * CH * H, H, b1, c1, v1, s1f, Bb, H, CH);
            gemm_lif_f32fb<<<dim3(H / 64, Bb / 64), blk, 0, stream>>>(
                s1f, H, W2, H, b2, nullptr, v2, s2f, Bb, H, H);
            gemm_lif_f32fb<<<dim3((O + 63) / 64, Bb / 64), blk, 0, stream>>>(
                s2f, H, W3, O, b3, nullptr, v3, out, Bb, O, H);
        }
        return;
    }

    // ---- prep: padded bias3 + 3-plane splits
    hipMemsetAsync(b3p, 0, 4096, stream);
    hipMemcpyAsync(b3p, b3, O * sizeof(float), hipMemcpyDeviceToDevice, stream);
    split3_t<<<dim3(H / 32, H / 32), 256, 0, stream>>>(W2, H, H, H, w2s);
    split3_t<<<dim3(H / 32, Op / 32), 256, 0, stream>>>(W3, H, O, Op, w3s);
    split3_w1<<<dim3(KP / 32, H / 32), 256, 0, stream>>>(W1, w1s);
    splitx<<<dim3((Bb * KP + 255) / 256), 256, 0, stream>>>(x, xs);

    const size_t PSx  = (size_t)Bb * KP;   // x plane stride
    const size_t PSw1 = (size_t)H * KP;
    const size_t PSw2 = (size_t)H * H;
    const size_t PSw3 = (size_t)Op * H;

    // ---- L1: P_t = x_t @ W1_t  (stacked M=10240, K=416 per block's t)
    gemm_planes<1><<<(MS / 128) * (H / 128), 256, 0, stream>>>(
        xs, PSx, KP, w1s, PSw1, KP, CHP, CHP, P, H, 1);
    // ---- LIF1 (prefix over t) -> s1 (bf16 spikes)
    lif_scan<<<(Bb * (H / 4) + 255) / 256, 256, 0, stream>>>(
        P, b1, (unsigned short*)s1, nullptr, H, H, 1);
    // ---- L2: C2 = s1_stack @ W2   (C2 aliases P)
    gemm_planes<0><<<(MS / 128) * (H / 128), 256, 0, stream>>>(
        s1, 0, H, w2s, PSw2, H, H, 0, P, H, 1);
    // ---- LIF2 -> s2 (aliases xs/w1s)
    lif_scan<<<(Bb * (H / 4) + 255) / 256, 256, 0, stream>>>(
        P, b2, (unsigned short*)s2, nullptr, H, H, 0);
    // ---- L3: C3 = s2_stack @ W3   (C3 aliases s1)
    gemm_planes<0><<<(MS / 128) * (Op / 128), 256, 0, stream>>>(
        s2, 0, H, w3s, PSw3, H, H, 0, C3, Op, 0);
    // ---- LIF3 -> out (t=9, n<1000)
    lif_scan<<<(Bb * (Op / 4) + 255) / 256, 256, 0, stream>>>(
        C3, b3p, nullptr, out, Op, O, 0);
}

// Round 6
// 523.209 us; speedup vs baseline: 2.7537x; 1.3829x over previous
//
#include <hip/hip_runtime.h>
#include <hip/hip_bf16.h>

// SNN 3-layer LIF MLP, T=10, fp32 reference.
// R6: fp16 2-plane splits (e5m10: hi+mid = 21+ mantissa bits, Sterbenz-exact
// residual) replace bf16 3-plane. Weights & x pre-scaled by 2^8 so mid-planes
// sit far above fp16's subnormal threshold; epilogue multiplies by exact 2^-8
// (L2/L3) or 2^-16 (L1). Both planes accumulate into ONE fp32 accumulator.
//   P_t  = x_t(2 planes) @ W1_t(2 planes), 3 pairs   [stacked M=10240]
//   LIF1 prefix-scan -> s1 (f16 spikes, exact)
//   C2   = s1 @ W2(2 planes);  LIF2 -> s2;  C3 = s2 @ W3(2 planes); LIF3 -> out
// GEMM: 128x128 tile, 256 thr, m97 2-barrier K-loop, global_load_lds 16B into
// XOR-granule-swizzled LDS (measured 0 bank conflicts R3/R5).

typedef _Float16 half8 __attribute__((ext_vector_type(8)));
typedef __attribute__((ext_vector_type(4))) float f32x4;
typedef __attribute__((ext_vector_type(4))) unsigned short us4;

#ifndef __has_builtin
#define __has_builtin(x) 0
#endif
#if __has_builtin(__builtin_amdgcn_global_load_lds)
#define HAS_GLLDS 1
#else
#define HAS_GLLDS 0
#endif

// ------------------------------------------------------------------ GEMM
// MODE 0: 1 A-plane (spikes) x 2 B-planes   wave tile 128m x 32n (FM=8,FN=2)
// MODE 1: 2 A-planes x 2 B-planes, 3 pairs  wave tile 64x64      (FM=4,FN=4)
//         per-t K-slice: t = m0>>10, kbase = t*kChunk
template<int MODE>
__global__ __launch_bounds__(256)
void gemm_planes(const _Float16* __restrict__ A, size_t aStride, int lda,
                 const _Float16* __restrict__ B, size_t bStride, int ldb,
                 int K, int kChunk, float scale,
                 float* __restrict__ C, int Npad, int ls)
{
    constexpr int NA = MODE ? 2 : 1;
    constexpr int NB = 2;
    constexpr int FM = MODE ? 4 : 8;
    constexpr int FN = MODE ? 4 : 2;

    __shared__ __align__(16) char tiles[(NA + NB) * 8192];

    const int tid = threadIdx.x;
    const int b   = blockIdx.x;
    const int xcd = b & 7, ii = b >> 3;
    const int ntp = 1 << ls;
    const int n_tile = xcd * ntp + (ii & (ntp - 1));
    const int m_tile = ii >> ls;
    const int m0 = m_tile * 128, n0 = n_tile * 128;

    const int t     = MODE ? (m0 >> 10) : 0;
    const int kbase = MODE ? t * kChunk : 0;
    const int arow0 = MODE ? (m0 & 1023) : m0;

    // staging decode: thread fills granule slots {tid, tid+256} of each plane
    int srow[2], schk[2];
    #pragma unroll
    for (int h = 0; h < 2; ++h) {
        const int s   = h * 256 + tid;
        const int sub = s >> 8, sp = s & 255;
        const int ss  = sp >> 3, gg = ((sp & 7) - ss) & 7;
        srow[h] = sub * 64 + 2 * ss + (gg >> 2);
        schk[h] = gg & 3;
    }
    const int wbase = (tid & ~63) * 16;   // wave-uniform LDS dest base

    const _Float16* srcA[NA][2];
    const _Float16* srcB[NB][2];
    #pragma unroll
    for (int p = 0; p < NA; ++p)
        #pragma unroll
        for (int h = 0; h < 2; ++h)
            srcA[p][h] = A + p * aStride + (size_t)(arow0 + srow[h]) * lda
                           + kbase + schk[h] * 8;
    #pragma unroll
    for (int q = 0; q < NB; ++q)
        #pragma unroll
        for (int h = 0; h < 2; ++h)
            srcB[q][h] = B + q * bStride + (size_t)(n0 + srow[h]) * ldb
                           + kbase + schk[h] * 8;

    // fragment geometry
    const int lane = tid & 63, w = tid >> 6;
    const int wm = MODE ? ((w >> 1) * 64) : 0;
    const int wn = MODE ? ((w & 1) * 64) : (w * 32);
    const int lm = lane & 15, ck = lane >> 4;

    int aOff[FM], bOff[FN];
    #pragma unroll
    for (int i = 0; i < FM; ++i) {
        const int r = wm + i * 16 + lm, sub = r >> 6, rr = r & 63, s2 = rr >> 1;
        aOff[i] = sub * 4096 + (s2 * 8 + ((((rr & 1) << 2) + ck + s2) & 7)) * 16;
    }
    #pragma unroll
    for (int j = 0; j < FN; ++j) {
        const int r = wn + j * 16 + lm, sub = r >> 6, rr = r & 63, s2 = rr >> 1;
        bOff[j] = sub * 4096 + (s2 * 8 + ((((rr & 1) << 2) + ck + s2) & 7)) * 16;
    }

    f32x4 acc[FM][FN] = {};

    const int nIter = K / 32;
    for (int it = 0; it < nIter; ++it) {
        const int kk = it * 32;
        #pragma unroll
        for (int p = 0; p < NA; ++p) {
            #pragma unroll
            for (int h = 0; h < 2; ++h) {
#if HAS_GLLDS
                __builtin_amdgcn_global_load_lds(
                    (const __attribute__((address_space(1))) void*)(srcA[p][h] + kk),
                    (__attribute__((address_space(3))) void*)(tiles + p * 8192 + h * 4096 + wbase),
                    16, 0, 0);
#else
                *(float4*)(tiles + p * 8192 + (h * 256 + tid) * 16) =
                    *(const float4*)(srcA[p][h] + kk);
#endif
            }
        }
        #pragma unroll
        for (int q = 0; q < NB; ++q) {
            #pragma unroll
            for (int h = 0; h < 2; ++h) {
#if HAS_GLLDS
                __builtin_amdgcn_global_load_lds(
                    (const __attribute__((address_space(1))) void*)(srcB[q][h] + kk),
                    (__attribute__((address_space(3))) void*)(tiles + (NA + q) * 8192 + h * 4096 + wbase),
                    16, 0, 0);
#else
                *(float4*)(tiles + (NA + q) * 8192 + (h * 256 + tid) * 16) =
                    *(const float4*)(srcB[q][h] + kk);
#endif
            }
        }
        __syncthreads();

        half8 aF[NA][FM], bF[NB][FN];
        #pragma unroll
        for (int p = 0; p < NA; ++p)
            #pragma unroll
            for (int i = 0; i < FM; ++i)
                aF[p][i] = *(const half8*)(tiles + p * 8192 + aOff[i]);
        #pragma unroll
        for (int q = 0; q < NB; ++q)
            #pragma unroll
            for (int j = 0; j < FN; ++j)
                bF[q][j] = *(const half8*)(tiles + (NA + q) * 8192 + bOff[j]);

        if (MODE == 0) {
            #pragma unroll
            for (int q = 0; q < 2; ++q)
                #pragma unroll
                for (int i = 0; i < FM; ++i)
                    #pragma unroll
                    for (int j = 0; j < FN; ++j)
                        acc[i][j] = __builtin_amdgcn_mfma_f32_16x16x32_f16(
                            aF[0][i], bF[q][j], acc[i][j], 0, 0, 0);
        } else {
            constexpr int PA[3] = {0,0,1}, PB[3] = {0,1,0};
            #pragma unroll
            for (int pp = 0; pp < 3; ++pp)
                #pragma unroll
                for (int i = 0; i < FM; ++i)
                    #pragma unroll
                    for (int j = 0; j < FN; ++j)
                        acc[i][j] = __builtin_amdgcn_mfma_f32_16x16x32_f16(
                            aF[PA[pp] % NA][i], bF[PB[pp]][j], acc[i][j], 0, 0, 0);
        }
        __syncthreads();
    }

    // scaled dot write. C/D layout: col = lane&15, row = (lane>>4)*4 + reg
    const int rq = ck * 4;
    #pragma unroll
    for (int i = 0; i < FM; ++i) {
        #pragma unroll
        for (int j = 0; j < FN; ++j) {
            const int n = n0 + wn + j * 16 + lm;
            #pragma unroll
            for (int r = 0; r < 4; ++r) {
                const int m = m0 + wm + i * 16 + rq + r;
                C[(size_t)m * Npad + n] = acc[i][j][r] * scale;
            }
        }
    }
}

// ------------------------------------------------------------------ LIF scan
// C stacked [T*1024][Hpad]; per (batch,neuron) scan over t with v in registers.
__global__ __launch_bounds__(256)
void lif_scan(const float* __restrict__ C, const float* __restrict__ bias,
              unsigned short* __restrict__ sout,   // f16 spike bits, nullable
              float* __restrict__ fout,            // nullable: t=9, n<Nreal
              int Hpad, int Nreal, int prefix)
{
    const int W4 = Hpad >> 2;
    const int idx = blockIdx.x * 256 + threadIdx.x;
    if (idx >= (W4 << 10)) return;
    const int bb = idx / W4, n4 = idx - bb * W4;
    const float4 b4 = *(const float4*)(bias + n4 * 4);
    const float bs[4] = {b4.x, b4.y, b4.z, b4.w};
    float v[4] = {0.f,0.f,0.f,0.f}, c[4] = {0.f,0.f,0.f,0.f};
    for (int t = 0; t < 10; ++t) {
        const size_t row = (size_t)((t << 10) + bb);
        const float4 p4 = *(const float4*)(C + row * Hpad + n4 * 4);
        const float pv[4] = {p4.x, p4.y, p4.z, p4.w};
        float sv[4];
        #pragma unroll
        for (int e = 0; e < 4; ++e) {
            c[e] = prefix ? (c[e] + pv[e]) : pv[e];
            const float vv = (v[e] + (c[e] + bs[e])) * 0.5f;
            const float sp = (vv >= 1.0f) ? 1.0f : 0.0f;
            v[e] = (sp != 0.0f) ? 0.0f : vv;
            sv[e] = sp;
        }
        if (sout) {
            us4 o;
            #pragma unroll
            for (int e = 0; e < 4; ++e) o[e] = (sv[e] != 0.0f) ? 0x3C00 : 0;  // f16 1.0
            *(us4*)(sout + row * Hpad + n4 * 4) = o;
        }
        if (fout && t == 9) {
            #pragma unroll
            for (int e = 0; e < 4; ++e) {
                const int n = n4 * 4 + e;
                if (n < Nreal) fout[(size_t)bb * Nreal + n] = sv[e];
            }
        }
    }
}

// ------------------------------------------------------------------ splits
// val_s = val * 256 (2^8); hi = f16(val_s); mid = f16(val_s - hi)  (Sterbenz)
__device__ __forceinline__ void f16split2(float val, _Float16& hi, _Float16& mid) {
    const float vs = val * 256.0f;
    hi = (_Float16)vs;
    mid = (_Float16)(vs - (float)hi);
}

// W [K][Nreal] fp32 -> 2 planes [Npad][K] f16 (NT), scaled 2^8
__global__ __launch_bounds__(256)
void split2_t(const float* __restrict__ W, int K, int Nreal, int Npad,
              _Float16* __restrict__ out)
{
    __shared__ float tl[32][33];
    const int k0 = blockIdx.x * 32, n0 = blockIdx.y * 32;
    const int tx = threadIdx.x & 31, ty = threadIdx.x >> 5;
    #pragma unroll
    for (int i = 0; i < 4; ++i) {
        const int k = k0 + ty + i * 8, n = n0 + tx;
        tl[ty + i * 8][tx] = (n < Nreal) ? W[(size_t)k * Nreal + n] : 0.f;
    }
    __syncthreads();
    const size_t plane = (size_t)Npad * K;
    #pragma unroll
    for (int i = 0; i < 4; ++i) {
        const int n = n0 + ty + i * 8, k = k0 + tx;
        _Float16 hi, mid;
        f16split2(tl[tx][ty + i * 8], hi, mid);
        const size_t idx = (size_t)n * K + k;
        out[idx] = hi; out[plane + idx] = mid;
    }
}

// W1 [4000][2048] -> 2 planes [2048][4160] f16 (NT, per-chunk K padded 400->416)
__global__ __launch_bounds__(256)
void split2_w1(const float* __restrict__ W1, _Float16* __restrict__ out)
{
    __shared__ float tl[32][33];
    const int kk0 = blockIdx.x * 32, n0 = blockIdx.y * 32;
    const int tx = threadIdx.x & 31, ty = threadIdx.x >> 5;
    #pragma unroll
    for (int i = 0; i < 4; ++i) {
        const int kk = kk0 + ty + i * 8;
        const int tt = kk / 416, j = kk - tt * 416;
        tl[ty + i * 8][tx] = (j < 400) ? W1[(size_t)(tt * 400 + j) * 2048 + (n0 + tx)] : 0.f;
    }
    __syncthreads();
    const size_t plane = (size_t)2048 * 4160;
    #pragma unroll
    for (int i = 0; i < 4; ++i) {
        const int n = n0 + ty + i * 8, kk = kk0 + tx;
        _Float16 hi, mid;
        f16split2(tl[tx][ty + i * 8], hi, mid);
        const size_t idx = (size_t)n * 4160 + kk;
        out[idx] = hi; out[plane + idx] = mid;
    }
}

// x [1024][4000] -> 2 planes [1024][4160] f16, scaled 2^8
__global__ __launch_bounds__(256)
void splitx(const float* __restrict__ x, _Float16* __restrict__ out)
{
    const int id = blockIdx.x * 256 + threadIdx.x;
    if (id >= 1024 * 4160) return;
    const int m = id / 4160, kk = id - m * 4160;
    const int tt = kk / 416, j = kk - tt * 416;
    const float val = (j < 400) ? x[(size_t)m * 4000 + tt * 400 + j] : 0.f;
    const size_t PS = (size_t)1024 * 4160;
    _Float16 hi, mid;
    f16split2(val, hi, mid);
    out[id] = hi; out[PS + id] = mid;
}

// -------------------------------------- fallback fp32 path (small workspace)
__global__ __launch_bounds__(256)
void gemm_lif_f32fb(const float* __restrict__ A, int lda,
                    const float* __restrict__ B, int ldb,
                    const float* __restrict__ bias,
                    float* __restrict__ cacc, float* __restrict__ v,
                    float* __restrict__ s, int M, int N, int K)
{
    __shared__ float As[16][68];
    __shared__ float Bs[16][68];
    const int tid = threadIdx.x;
    const int tx = tid & 15, ty = tid >> 4;
    const int row0 = blockIdx.y * 64, col0 = blockIdx.x * 64;
    const int am = tid >> 2, ak = (tid & 3) * 4;
    const int bk = tid >> 4, bn = (tid & 15) * 4;
    float acc[4][4];
    #pragma unroll
    for (int i = 0; i < 4; ++i)
        #pragma unroll
        for (int j = 0; j < 4; ++j) acc[i][j] = 0.f;
    for (int k0 = 0; k0 < K; k0 += 16) {
        const float4 a4 = *(const float4*)(A + (size_t)(row0 + am) * lda + (k0 + ak));
        As[ak + 0][am] = a4.x; As[ak + 1][am] = a4.y;
        As[ak + 2][am] = a4.z; As[ak + 3][am] = a4.w;
        {
            const int col = col0 + bn;
            const float* bp = B + (size_t)(k0 + bk) * ldb + col;
            float4 b4;
            if (col + 3 < N) b4 = *(const float4*)bp;
            else {
                b4.x = (col + 0 < N) ? bp[0] : 0.f;
                b4.y = (col + 1 < N) ? bp[1] : 0.f;
                b4.z = (col + 2 < N) ? bp[2] : 0.f;
                b4.w = 0.f;
            }
            *(float4*)&Bs[bk][bn] = b4;
        }
        __syncthreads();
        #pragma unroll
        for (int kk = 0; kk < 16; ++kk) {
            float af[4], bf[4];
            #pragma unroll
            for (int i = 0; i < 4; ++i) af[i] = As[kk][ty * 4 + i];
            #pragma unroll
            for (int j = 0; j < 4; ++j) bf[j] = Bs[kk][tx * 4 + j];
            #pragma unroll
            for (int i = 0; i < 4; ++i)
                #pragma unroll
                for (int j = 0; j < 4; ++j) acc[i][j] += af[i] * bf[j];
        }
        __syncthreads();
    }
    #pragma unroll
    for (int i = 0; i < 4; ++i) {
        const int r = row0 + ty * 4 + i;
        #pragma unroll
        for (int j = 0; j < 4; ++j) {
            const int cidx = col0 + tx * 4 + j;
            if (cidx >= N) continue;
            const size_t idx = (size_t)r * N + cidx;
            float dot = acc[i][j];
            if (cacc) { dot += cacc[idx]; cacc[idx] = dot; }
            const float ch = dot + bias[cidx];
            const float vv = (v[idx] + ch) * 0.5f;
            const float sp = (vv >= 1.0f) ? 1.0f : 0.0f;
            v[idx] = (sp != 0.0f) ? 0.0f : vv;
            s[idx] = sp;
        }
    }
}

// --------------------------------------------------------------------- launch
extern "C" void kernel_launch(void* const* d_in, const int* in_sizes, int n_in,
                              void* d_out, int out_size, void* d_ws, size_t ws_size,
                              hipStream_t stream) {
    const float* x  = (const float*)d_in[0];
    const float* W1 = (const float*)d_in[1];
    const float* b1 = (const float*)d_in[2];
    const float* W2 = (const float*)d_in[3];
    const float* b2 = (const float*)d_in[4];
    const float* W3 = (const float*)d_in[5];
    const float* b3 = (const float*)d_in[6];
    float* out = (float*)d_out;

    const int Bb = 1024, D = 4000, H = 2048, O = 1000, Op = 1024, T = 10;
    const int KP = 4160, CHP = 416, CH = 400;
    const int MS = T * Bb;   // 10240 stacked rows
    const float SC1 = 1.0f / 65536.0f;   // 2^-16 (x and W1 both 2^8-scaled)
    const float SC23 = 1.0f / 256.0f;    // 2^-8  (spikes unscaled, W 2^8-scaled)

    // ---- workspace layout (byte offsets, all 4 KiB aligned)
    char* base = (char*)d_ws;
    _Float16* w2s = (_Float16*)(base);                  // 16,777,216
    _Float16* w3s = (_Float16*)(base + 16777216);       //  8,388,608
    float*    b3p = (float*)(base + 25165824);          //      4,096
    _Float16* s1  = (_Float16*)(base + 25169920);       // 41,943,040
    float*    P   = (float*)(base + 67112960);          // 83,886,080 (C2 alias)
    _Float16* xs  = (_Float16*)(base + 150999040);      // 17,039,360
    _Float16* w1s = (_Float16*)(base + 168038400);      // 34,078,720
    _Float16* s2  = xs;          // alias: xs/w1s dead after L1 gemm (51 MB avail)
    float*    C3  = (float*)s1;  // alias: s1 dead after L2 gemm (42 MB exactly)
    const size_t need = 202117120;

    if (ws_size < need) {
        // fp32 VALU fallback (R1 path, ~3.5 ms, 46 MB)
        const size_t BH = (size_t)Bb * H, BO = (size_t)Bb * O;
        float* ws = (float*)d_ws;
        float* c1 = ws;        float* v1 = c1 + BH;  float* s1f = v1 + BH;
        float* v2 = s1f + BH;  float* s2f = v2 + BH; float* v3 = s2f + BH;
        hipMemsetAsync(d_ws, 0, (5 * BH + BO) * sizeof(float), stream);
        const dim3 blk(256);
        for (int t = 0; t < T; ++t) {
            gemm_lif_f32fb<<<dim3(H / 64, Bb / 64), blk, 0, stream>>>(
                x + t * CH, D, W1 + (size_t)t * CH * H, H, b1, c1, v1, s1f, Bb, H, CH);
            gemm_lif_f32fb<<<dim3(H / 64, Bb / 64), blk, 0, stream>>>(
                s1f, H, W2, H, b2, nullptr, v2, s2f, Bb, H, H);
            gemm_lif_f32fb<<<dim3((O + 63) / 64, Bb / 64), blk, 0, stream>>>(
                s2f, H, W3, O, b3, nullptr, v3, out, Bb, O, H);
        }
        return;
    }

    // ---- prep: padded bias3 + 2-plane f16 splits (2^8-scaled)
    hipMemsetAsync(b3p, 0, 4096, stream);
    hipMemcpyAsync(b3p, b3, O * sizeof(float), hipMemcpyDeviceToDevice, stream);
    split2_t<<<dim3(H / 32, H / 32), 256, 0, stream>>>(W2, H, H, H, w2s);
    split2_t<<<dim3(H / 32, Op / 32), 256, 0, stream>>>(W3, H, O, Op, w3s);
    split2_w1<<<dim3(KP / 32, H / 32), 256, 0, stream>>>(W1, w1s);
    splitx<<<dim3((Bb * KP + 255) / 256), 256, 0, stream>>>(x, xs);

    const size_t PSx  = (size_t)Bb * KP;   // x plane stride
    const size_t PSw1 = (size_t)H * KP;
    const size_t PSw2 = (size_t)H * H;
    const size_t PSw3 = (size_t)Op * H;

    // ---- L1: P_t = x_t @ W1_t  (stacked M=10240, K=416 per block's t)
    gemm_planes<1><<<(MS / 128) * (H / 128), 256, 0, stream>>>(
        xs, PSx, KP, w1s, PSw1, KP, CHP, CHP, SC1, P, H, 1);
    // ---- LIF1 (prefix over t) -> s1 (f16 spikes)
    lif_scan<<<(Bb * (H / 4) + 255) / 256, 256, 0, stream>>>(
        P, b1, (unsigned short*)s1, nullptr, H, H, 1);
    // ---- L2: C2 = s1_stack @ W2   (C2 aliases P)
    gemm_planes<0><<<(MS / 128) * (H / 128), 256, 0, stream>>>(
        s1, 0, H, w2s, PSw2, H, H, 0, SC23, P, H, 1);
    // ---- LIF2 -> s2 (aliases xs/w1s)
    lif_scan<<<(Bb * (H / 4) + 255) / 256, 256, 0, stream>>>(
        P, b2, (unsigned short*)s2, nullptr, H, H, 0);
    // ---- L3: C3 = s2_stack @ W3   (C3 aliases s1)
    gemm_planes<0><<<(MS / 128) * (Op / 128), 256, 0, stream>>>(
        s2, 0, H, w3s, PSw3, H, H, 0, SC23, C3, Op, 0);
    // ---- LIF3 -> out (t=9, n<1000)
    lif_scan<<<(Bb * (Op / 4) + 255) / 256, 256, 0, stream>>>(
        C3, b3p, nullptr, out, Op, O, 0);
}